// Round 9
// baseline (54.726 us; speedup 1.0000x reference)
//
#include <hip/hip_runtime.h>
#include <hip/hip_bf16.h>

#define LSEQ 256
#define EDIM 256
#define HNUM 8
#define DDIM 32
#define NBAT 4

// workspace layout (in floats)
#define OFF_QS   0                          // N*L*E scaled q-proj
#define OFF_KP   (NBAT*LSEQ*EDIM)           // N*L*E k-proj
#define OFF_VP   (2*NBAT*LSEQ*EDIM)         // N*L*E v-proj
#define OFF_WOT  (3*NBAT*LSEQ*EDIM)         // E*E  Wout transposed
#define OFF_WA   (3*NBAT*LSEQ*EDIM + EDIM*EDIM)  // 32
#define OFF_WR   (OFF_WA + 32)              // 32
#define OFF_BS   (OFF_WR + 32)              // 1
#define OFF_EN   852096                     // 64-aligned; N*L*L*H energies (bf16)
#define WS_NEED_FLOATS (OFF_EN + NBAT*LSEQ*LSEQ*HNUM)  // conservative (bf16 uses half)

typedef float f32x4_t __attribute__((ext_vector_type(4)));

__device__ __forceinline__ float bf16_to_f32(unsigned int u16) {
    return __uint_as_float(u16 << 16);
}

// ---- prep_all: one launch (R5-proven: 4 rows/block, 273 blocks) -------------
// blocks 0..255  : per-(n,l) q/k/v per-head projections, 4 rows per block
// blocks 256..271: Wout transpose tiles
// block  272     : wr_eff + bsum (for energy kernel)
__global__ __launch_bounds__(256)
void prep_all(const float* __restrict__ query, const float* __restrict__ keys,
              const float* __restrict__ values,
              const float* __restrict__ Wq, const float* __restrict__ Wk,
              const float* __restrict__ Wv,
              const float* __restrict__ Wfuse, const float* __restrict__ bfuse,
              const float* __restrict__ Wr, const float* __restrict__ Wout,
              float* __restrict__ ws) {
    int t = threadIdx.x;
    int b = blockIdx.x;
    if (b < 256) {
        __shared__ float xq[4][EDIM], xk[4][EDIM], xv[4][EDIM];
        __shared__ float wqT[DDIM][DDIM + 1], wkT[DDIM][DDIM + 1], wvT[DDIM][DDIM + 1];
        __shared__ float swA[DDIM];
        int row0 = b * 4;
#pragma unroll
        for (int rr = 0; rr < 4; ++rr) {
            xq[rr][t] = query[(row0 + rr) * EDIM + t];
            xk[rr][t] = keys[(row0 + rr) * EDIM + t];
            xv[rr][t] = values[(row0 + rr) * EDIM + t];
        }
        for (int c = t; c < DDIM * DDIM; c += 256) {
            int o = c / DDIM, d = c % DDIM;
            wqT[d][o] = Wq[c];
            wkT[d][o] = Wk[c];
            wvT[d][o] = Wv[c];
        }
        if (t < DDIM) {
            float s = 0.f;
            for (int d = 0; d < DDIM; ++d) s += Wfuse[d * 2 * DDIM + t];
            swA[t] = s;
        }
        __syncthreads();
        int o = t & (DDIM - 1), h = t >> 5;
#pragma unroll
        for (int rr = 0; rr < 4; ++rr) {
            float aq = 0.f, ak = 0.f, av = 0.f;
            for (int d = 0; d < DDIM; ++d) {
                float q_ = xq[rr][h * DDIM + d], k_ = xk[rr][h * DDIM + d], v_ = xv[rr][h * DDIM + d];
                aq += q_ * wqT[d][o];
                ak += k_ * wkT[d][o];
                av += v_ * wvT[d][o];
            }
            ws[OFF_QS + (row0 + rr) * EDIM + t] = aq * swA[o];
            ws[OFF_KP + (row0 + rr) * EDIM + t] = ak;
            ws[OFF_VP + (row0 + rr) * EDIM + t] = av;
        }
    } else if (b < 272) {
        __shared__ float tile[64][65];
        int bb = b - 256;
        int br = bb >> 2, bc = bb & 3;
        int R0 = br * 64, C0 = bc * 64;
        for (int idx = t; idx < 4096; idx += 256) {
            int lr = idx >> 6, lc = idx & 63;
            tile[lr][lc] = Wout[(R0 + lr) * EDIM + C0 + lc];
        }
        __syncthreads();
        for (int idx = t; idx < 4096; idx += 256) {
            int lr = idx >> 6, lc = idx & 63;
            ws[OFF_WOT + (C0 + lr) * EDIM + R0 + lc] = tile[lc][lr];
        }
    } else {
        __shared__ float sWB[DDIM];
        if (t >= DDIM && t < 2 * DDIM) {
            float s = 0.f;
            for (int d = 0; d < DDIM; ++d) s += Wfuse[d * 2 * DDIM + t];
            sWB[t - DDIM] = s;
        }
        if (t == 0) {
            float bs = 0.f;
            for (int d = 0; d < DDIM; ++d) bs += bfuse[d];
            ws[OFF_BS] = bs;
        }
        __syncthreads();
        if (t < DDIM) {
            float s = 0.f;
            for (int o = 0; o < DDIM; ++o) s += sWB[o] * Wr[o * DDIM + t];
            ws[OFF_WR + t] = s;
        }
    }
}

// ---- energy: relation stream with mask-skip (R5 structure, bf16 en, nt loads)
// wave w handles (nq = w>>4), k in [ (w&15)*16, +16 ); writes en[nq*2048+k*8+h]
__global__ __launch_bounds__(256, 6)
void energy_kernel(const float* __restrict__ relation, const int* __restrict__ mask,
                   const float* __restrict__ ws, __hip_bfloat16* __restrict__ en) {
    int t = threadIdx.x;
    int lane = t & 63, wid = t >> 6;
    int wgl = blockIdx.x * 4 + wid;      // 0..16383
    int nq = wgl >> 4;                   // 0..1023
    int k0 = (wgl & 15) * 16;
    int n = nq >> 8;
    int h = lane >> 3;

    const float4* qs4 = reinterpret_cast<const float4*>(ws + OFF_QS);
    const float4* wr4 = reinterpret_cast<const float4*>(ws + OFF_WR);
    float4 qv = qs4[(size_t)nq * 64 + lane];
    float4 wv = wr4[lane & 7];
    float bsum = ws[OFF_BS];

    const f32x4_t* rel4 = reinterpret_cast<const f32x4_t*>(relation)
                          + (size_t)nq * LSEQ * (EDIM / 4);
    const float4* kp4  = reinterpret_cast<const float4*>(ws + OFF_KP)
                         + (size_t)n * LSEQ * (EDIM / 4);
    const int* mrow = mask + nq * LSEQ;
    __hip_bfloat16* erow = en + (size_t)nq * (LSEQ * HNUM);

    // preload the wave's 16 mask values (wave-uniform -> scalar loads)
    int mks[16];
#pragma unroll
    for (int j = 0; j < 16; ++j) mks[j] = mrow[k0 + j];

#pragma unroll
    for (int j = 0; j < 16; ++j) {
        int k = k0 + j;
        if (mks[j]) {
            if ((lane & 7) == 0) erow[k * HNUM + h] = __float2bfloat16(-6.25e18f);
        } else {
            f32x4_t rv = __builtin_nontemporal_load(&rel4[(size_t)k * (EDIM / 4) + lane]);
            float4 kv = kp4[(size_t)k * (EDIM / 4) + lane];
            float p = rv.x * wv.x + rv.y * wv.y + rv.z * wv.z + rv.w * wv.w
                    + qv.x * kv.x + qv.y * kv.y + qv.z * kv.z + qv.w * kv.w;
            p += __shfl_xor(p, 1);
            p += __shfl_xor(p, 2);
            p += __shfl_xor(p, 4);
            if ((lane & 7) == 0) erow[k * HNUM + h] = __float2bfloat16((p + bsum) * 0.0625f);
        }
    }
}

// ---- tail: softmax + PV + Wout projection, 4 q-rows per block, 1024 thr -----
__global__ __launch_bounds__(1024)
void attn_tail4(const __hip_bfloat16* __restrict__ en, const float* __restrict__ ws,
                const float* __restrict__ bout, float* __restrict__ out) {
    __shared__ float att[4][HNUM][LSEQ + 1];   // ~32.9 KB
    __shared__ float part[16][4][EDIM];        // 64 KB
    __shared__ float accsm[4][EDIM];           // 4 KB

    int t = threadIdx.x;            // 0..1023
    int nq0 = blockIdx.x * 4;       // all 4 rows share n
    int n = nq0 >> 8;
    int lane = t & 63, wid = t >> 6;   // 16 waves
    int e0 = 4 * lane;
    int hh = lane >> 3;

    // load 4 energy rows: 4*2048 bf16; one uint4 (=8 bf16 = all heads of one k)
    // per thread: j = qq*256 + k
    {
        const uint4* enu = reinterpret_cast<const uint4*>(en + (size_t)nq0 * 2048);
        uint4 v = enu[t];
        int qq = t >> 8, k = t & 255;
        att[qq][0][k] = bf16_to_f32(v.x & 0xffffu);
        att[qq][1][k] = bf16_to_f32(v.x >> 16);
        att[qq][2][k] = bf16_to_f32(v.y & 0xffffu);
        att[qq][3][k] = bf16_to_f32(v.y >> 16);
        att[qq][4][k] = bf16_to_f32(v.z & 0xffffu);
        att[qq][5][k] = bf16_to_f32(v.z >> 16);
        att[qq][6][k] = bf16_to_f32(v.w & 0xffffu);
        att[qq][7][k] = bf16_to_f32(v.w >> 16);
    }
    __syncthreads();

    // softmax: 1024 threads = (4q x 8h) rows x 32 sub, each owns 8 elements
    {
        int row = t >> 5, sub = t & 31;   // row: qq*8+h
        int qq = row >> 3, h = row & 7;
        float m = -3.4e38f;
        for (int jj = 0; jj < 8; ++jj) m = fmaxf(m, att[qq][h][sub + jj * 32]);
        for (int off = 1; off < 32; off <<= 1) m = fmaxf(m, __shfl_xor(m, off));
        float ex[8];
        float ssum = 0.f;
        for (int jj = 0; jj < 8; ++jj) {
            float e_ = __expf(att[qq][h][sub + jj * 32] - m);
            ex[jj] = e_;
            ssum += e_;
        }
        for (int off = 1; off < 32; off <<= 1) ssum += __shfl_xor(ssum, off);
        float inv = 1.0f / ssum;
        for (int jj = 0; jj < 8; ++jj) att[qq][h][sub + jj * 32] = ex[jj] * inv;
    }
    __syncthreads();

    // PV: k split over 16 waves (16 each); each vv load feeds all 4 q-rows
    const float4* vp4 = reinterpret_cast<const float4*>(ws + OFF_VP)
                        + (size_t)n * LSEQ * (EDIM / 4);
    {
        float4 a0 = {0,0,0,0}, a1 = {0,0,0,0}, a2 = {0,0,0,0}, a3 = {0,0,0,0};
#pragma unroll 4
        for (int kk = 0; kk < 16; ++kk) {
            int k = wid * 16 + kk;
            float4 vv = vp4[(size_t)k * (EDIM / 4) + lane];
            float s0 = att[0][hh][k], s1 = att[1][hh][k];
            float s2 = att[2][hh][k], s3 = att[3][hh][k];
            a0.x += s0 * vv.x; a0.y += s0 * vv.y; a0.z += s0 * vv.z; a0.w += s0 * vv.w;
            a1.x += s1 * vv.x; a1.y += s1 * vv.y; a1.z += s1 * vv.z; a1.w += s1 * vv.w;
            a2.x += s2 * vv.x; a2.y += s2 * vv.y; a2.z += s2 * vv.z; a2.w += s2 * vv.w;
            a3.x += s3 * vv.x; a3.y += s3 * vv.y; a3.z += s3 * vv.z; a3.w += s3 * vv.w;
        }
        *reinterpret_cast<float4*>(&part[wid][0][e0]) = a0;
        *reinterpret_cast<float4*>(&part[wid][1][e0]) = a1;
        *reinterpret_cast<float4*>(&part[wid][2][e0]) = a2;
        *reinterpret_cast<float4*>(&part[wid][3][e0]) = a3;
    }
    __syncthreads();
    {
        int qq = t >> 8, e = t & 255;
        float s = 0.f;
#pragma unroll
        for (int w = 0; w < 16; ++w) s += part[w][qq][e];
        accsm[qq][e] = s;
    }
    __syncthreads();

    // final projection: e' split over 16 waves (16 each); w load feeds 4 rows
    const float4* wo4 = reinterpret_cast<const float4*>(ws + OFF_WOT);
    {
        float4 o0 = {0,0,0,0}, o1 = {0,0,0,0}, o2 = {0,0,0,0}, o3 = {0,0,0,0};
#pragma unroll 4
        for (int ee = 0; ee < 16; ++ee) {
            int ep = wid * 16 + ee;
            float a0 = accsm[0][ep], a1 = accsm[1][ep];
            float a2 = accsm[2][ep], a3 = accsm[3][ep];
            float4 w = wo4[(size_t)ep * (EDIM / 4) + lane];
            o0.x += a0 * w.x; o0.y += a0 * w.y; o0.z += a0 * w.z; o0.w += a0 * w.w;
            o1.x += a1 * w.x; o1.y += a1 * w.y; o1.z += a1 * w.z; o1.w += a1 * w.w;
            o2.x += a2 * w.x; o2.y += a2 * w.y; o2.z += a2 * w.z; o2.w += a2 * w.w;
            o3.x += a3 * w.x; o3.y += a3 * w.y; o3.z += a3 * w.z; o3.w += a3 * w.w;
        }
        *reinterpret_cast<float4*>(&part[wid][0][e0]) = o0;
        *reinterpret_cast<float4*>(&part[wid][1][e0]) = o1;
        *reinterpret_cast<float4*>(&part[wid][2][e0]) = o2;
        *reinterpret_cast<float4*>(&part[wid][3][e0]) = o3;
    }
    __syncthreads();
    {
        int qq = t >> 8, e = t & 255;
        float s = bout[e];
#pragma unroll
        for (int w = 0; w < 16; ++w) s += part[w][qq][e];
        out[(size_t)(nq0 + qq) * EDIM + e] = s;
    }
}

// ---- fallback fused kernel (R0, proven): used only if ws too small ----------
__global__ __launch_bounds__(256)
void attn_main(const float* __restrict__ relation, const int* __restrict__ mask,
               const float* __restrict__ ws, const float* __restrict__ bout,
               float* __restrict__ out) {
    __shared__ float qs[EDIM];
    __shared__ float wrf[EDIM];
    __shared__ int   mrow[LSEQ];
    __shared__ float energy[HNUM][LSEQ + 1];
    __shared__ float part[4][EDIM];
    __shared__ float accsm[EDIM];
    __shared__ float sb;

    int t = threadIdx.x;
    int bid = blockIdx.x;
    int n = bid >> 8, qi = bid & 255;
    int lane = t & 63, wid = t >> 6;

    qs[t]  = ws[OFF_QS + (n * LSEQ + qi) * EDIM + t];
    wrf[t] = ws[OFF_WR + (t & (DDIM - 1))];
    mrow[t] = mask[(n * LSEQ + qi) * LSEQ + t];
    if (t == 0) sb = ws[OFF_BS];
    __syncthreads();
    float bsum = sb;

    const float4* rel4 = reinterpret_cast<const float4*>(relation)
                         + (size_t)(n * LSEQ + qi) * LSEQ * (EDIM / 4);
    const float4* kp4  = reinterpret_cast<const float4*>(ws + OFF_KP)
                         + (size_t)n * LSEQ * (EDIM / 4);
    int e0 = 4 * lane;
    int hh = lane >> 3;
    float4 qv = *reinterpret_cast<const float4*>(&qs[e0]);
    float4 wv = *reinterpret_cast<const float4*>(&wrf[e0]);
    for (int it = 0; it < 64; ++it) {
        int k = it * 4 + wid;
        float4 rv = rel4[(size_t)k * (EDIM / 4) + lane];
        float4 kv = kp4[(size_t)k * (EDIM / 4) + lane];
        float p = rv.x * wv.x + rv.y * wv.y + rv.z * wv.z + rv.w * wv.w
                + qv.x * kv.x + qv.y * kv.y + qv.z * kv.z + qv.w * kv.w;
        p += __shfl_xor(p, 1);
        p += __shfl_xor(p, 2);
        p += __shfl_xor(p, 4);
        if ((lane & 7) == 0) {
            float val = mrow[k] ? -1e20f : (p + bsum);
            energy[hh][k] = val * 0.0625f;
        }
    }
    __syncthreads();

    {
        int h = t >> 5, sub = t & 31;
        float m = -3.4e38f;
        for (int jj = 0; jj < 8; ++jj) m = fmaxf(m, energy[h][sub + jj * 32]);
        for (int off = 1; off < 32; off <<= 1) m = fmaxf(m, __shfl_xor(m, off));
        float ex[8];
        float ssum = 0.f;
        for (int jj = 0; jj < 8; ++jj) {
            float e_ = __expf(energy[h][sub + jj * 32] - m);
            ex[jj] = e_;
            ssum += e_;
        }
        for (int off = 1; off < 32; off <<= 1) ssum += __shfl_xor(ssum, off);
        float inv = 1.0f / ssum;
        for (int jj = 0; jj < 8; ++jj) energy[h][sub + jj * 32] = ex[jj] * inv;
    }
    __syncthreads();

    const float4* vp4 = reinterpret_cast<const float4*>(ws + OFF_VP)
                        + (size_t)n * LSEQ * (EDIM / 4);
    {
        float4 a4 = {0.f, 0.f, 0.f, 0.f};
        for (int kk = 0; kk < 64; ++kk) {
            int k = wid * 64 + kk;
            float4 vv = vp4[(size_t)k * (EDIM / 4) + lane];
            float a = energy[hh][k];
            a4.x += a * vv.x; a4.y += a * vv.y; a4.z += a * vv.z; a4.w += a * vv.w;
        }
        *reinterpret_cast<float4*>(&part[wid][e0]) = a4;
    }
    __syncthreads();
    accsm[t] = part[0][t] + part[1][t] + part[2][t] + part[3][t];
    __syncthreads();

    const float4* wo4 = reinterpret_cast<const float4*>(ws + OFF_WOT);
    {
        float4 o4 = {0.f, 0.f, 0.f, 0.f};
        for (int ee = 0; ee < 64; ++ee) {
            int ep = wid * 64 + ee;
            float a = accsm[ep];
            float4 w = wo4[(size_t)ep * (EDIM / 4) + lane];
            o4.x += a * w.x; o4.y += a * w.y; o4.z += a * w.z; o4.w += a * w.w;
        }
        *reinterpret_cast<float4*>(&part[wid][e0]) = o4;
    }
    __syncthreads();
    out[(n * LSEQ + qi) * EDIM + t] =
        part[0][t] + part[1][t] + part[2][t] + part[3][t] + bout[t];
}

extern "C" void kernel_launch(void* const* d_in, const int* in_sizes, int n_in,
                              void* d_out, int out_size, void* d_ws, size_t ws_size,
                              hipStream_t stream) {
    const float* values   = (const float*)d_in[0];
    const float* keys     = (const float*)d_in[1];
    const float* query    = (const float*)d_in[2];
    const int*   mask     = (const int*)d_in[3];
    const float* relation = (const float*)d_in[4];
    const float* Wv    = (const float*)d_in[5];
    const float* Wk    = (const float*)d_in[6];
    const float* Wq    = (const float*)d_in[7];
    const float* Wr    = (const float*)d_in[8];
    const float* Wfuse = (const float*)d_in[9];
    const float* bfuse = (const float*)d_in[10];
    const float* Wout  = (const float*)d_in[11];
    const float* bout  = (const float*)d_in[12];
    float* ws  = (float*)d_ws;
    float* out = (float*)d_out;

    prep_all<<<273, 256, 0, stream>>>(query, keys, values,
                                      Wq, Wk, Wv, Wfuse, bfuse,
                                      Wr, Wout, ws);

    if (ws_size >= (size_t)WS_NEED_FLOATS * sizeof(float)) {
        __hip_bfloat16* en = reinterpret_cast<__hip_bfloat16*>(ws + OFF_EN);
        energy_kernel<<<4096, 256, 0, stream>>>(relation, mask, ws, en);
        attn_tail4<<<NBAT * LSEQ / 4, 1024, 0, stream>>>(en, ws, bout, out);
    } else {
        attn_main<<<NBAT * LSEQ, 256, 0, stream>>>(relation, mask, ws, bout, out);
    }
}

// Round 10
// 47.298 us; speedup vs baseline: 1.1571x; 1.1571x over previous
//
#include <hip/hip_runtime.h>
#include <hip/hip_bf16.h>

#define LSEQ 256
#define EDIM 256
#define HNUM 8
#define DDIM 32
#define NBAT 4

// workspace layout (in floats)
#define OFF_QS   0                          // N*L*E scaled q-proj
#define OFF_KP   (NBAT*LSEQ*EDIM)           // N*L*E k-proj
#define OFF_VP   (2*NBAT*LSEQ*EDIM)         // N*L*E v-proj
#define OFF_WOT  (3*NBAT*LSEQ*EDIM)         // E*E  Wout transposed
#define OFF_WA   (3*NBAT*LSEQ*EDIM + EDIM*EDIM)  // 32
#define OFF_WR   (OFF_WA + 32)              // 32
#define OFF_BS   (OFF_WR + 32)              // 1
#define OFF_EN   852096                     // 64-aligned; N*L*L*H energies (bf16)
#define WS_NEED_FLOATS (OFF_EN + NBAT*LSEQ*LSEQ*HNUM)  // conservative (bf16 uses half)

__device__ __forceinline__ float bf16_to_f32(unsigned int u16) {
    return __uint_as_float(u16 << 16);
}

// ---- prep_all: one launch (R5-proven: 4 rows/block, 273 blocks) -------------
// blocks 0..255  : per-(n,l) q/k/v per-head projections, 4 rows per block
// blocks 256..271: Wout transpose tiles
// block  272     : wr_eff + bsum (for energy kernel)
__global__ __launch_bounds__(256)
void prep_all(const float* __restrict__ query, const float* __restrict__ keys,
              const float* __restrict__ values,
              const float* __restrict__ Wq, const float* __restrict__ Wk,
              const float* __restrict__ Wv,
              const float* __restrict__ Wfuse, const float* __restrict__ bfuse,
              const float* __restrict__ Wr, const float* __restrict__ Wout,
              float* __restrict__ ws) {
    int t = threadIdx.x;
    int b = blockIdx.x;
    if (b < 256) {
        __shared__ float xq[4][EDIM], xk[4][EDIM], xv[4][EDIM];
        __shared__ float wqT[DDIM][DDIM + 1], wkT[DDIM][DDIM + 1], wvT[DDIM][DDIM + 1];
        __shared__ float swA[DDIM];
        int row0 = b * 4;
#pragma unroll
        for (int rr = 0; rr < 4; ++rr) {
            xq[rr][t] = query[(row0 + rr) * EDIM + t];
            xk[rr][t] = keys[(row0 + rr) * EDIM + t];
            xv[rr][t] = values[(row0 + rr) * EDIM + t];
        }
        for (int c = t; c < DDIM * DDIM; c += 256) {
            int o = c / DDIM, d = c % DDIM;
            wqT[d][o] = Wq[c];
            wkT[d][o] = Wk[c];
            wvT[d][o] = Wv[c];
        }
        if (t < DDIM) {
            float s = 0.f;
            for (int d = 0; d < DDIM; ++d) s += Wfuse[d * 2 * DDIM + t];
            swA[t] = s;
        }
        __syncthreads();
        int o = t & (DDIM - 1), h = t >> 5;
#pragma unroll
        for (int rr = 0; rr < 4; ++rr) {
            float aq = 0.f, ak = 0.f, av = 0.f;
            for (int d = 0; d < DDIM; ++d) {
                float q_ = xq[rr][h * DDIM + d], k_ = xk[rr][h * DDIM + d], v_ = xv[rr][h * DDIM + d];
                aq += q_ * wqT[d][o];
                ak += k_ * wkT[d][o];
                av += v_ * wvT[d][o];
            }
            ws[OFF_QS + (row0 + rr) * EDIM + t] = aq * swA[o];
            ws[OFF_KP + (row0 + rr) * EDIM + t] = ak;
            ws[OFF_VP + (row0 + rr) * EDIM + t] = av;
        }
    } else if (b < 272) {
        __shared__ float tile[64][65];
        int bb = b - 256;
        int br = bb >> 2, bc = bb & 3;
        int R0 = br * 64, C0 = bc * 64;
        for (int idx = t; idx < 4096; idx += 256) {
            int lr = idx >> 6, lc = idx & 63;
            tile[lr][lc] = Wout[(R0 + lr) * EDIM + C0 + lc];
        }
        __syncthreads();
        for (int idx = t; idx < 4096; idx += 256) {
            int lr = idx >> 6, lc = idx & 63;
            ws[OFF_WOT + (C0 + lr) * EDIM + R0 + lc] = tile[lc][lr];
        }
    } else {
        __shared__ float sWB[DDIM];
        if (t >= DDIM && t < 2 * DDIM) {
            float s = 0.f;
            for (int d = 0; d < DDIM; ++d) s += Wfuse[d * 2 * DDIM + t];
            sWB[t - DDIM] = s;
        }
        if (t == 0) {
            float bs = 0.f;
            for (int d = 0; d < DDIM; ++d) bs += bfuse[d];
            ws[OFF_BS] = bs;
        }
        __syncthreads();
        if (t < DDIM) {
            float s = 0.f;
            for (int o = 0; o < DDIM; ++o) s += sWB[o] * Wr[o * DDIM + t];
            ws[OFF_WR + t] = s;
        }
    }
}

// ---- energy: relation stream with mask-skip (R5 structure, bf16 en) --------
// wave w handles (nq = w>>4), k in [ (w&15)*16, +16 ); writes en[nq*2048+k*8+h]
__global__ __launch_bounds__(256, 6)
void energy_kernel(const float* __restrict__ relation, const int* __restrict__ mask,
                   const float* __restrict__ ws, __hip_bfloat16* __restrict__ en) {
    int t = threadIdx.x;
    int lane = t & 63, wid = t >> 6;
    int wgl = blockIdx.x * 4 + wid;      // 0..16383
    int nq = wgl >> 4;                   // 0..1023
    int k0 = (wgl & 15) * 16;
    int n = nq >> 8;
    int h = lane >> 3;

    const float4* qs4 = reinterpret_cast<const float4*>(ws + OFF_QS);
    const float4* wr4 = reinterpret_cast<const float4*>(ws + OFF_WR);
    float4 qv = qs4[(size_t)nq * 64 + lane];
    float4 wv = wr4[lane & 7];
    float bsum = ws[OFF_BS];

    const float4* rel4 = reinterpret_cast<const float4*>(relation)
                         + (size_t)nq * LSEQ * (EDIM / 4);
    const float4* kp4  = reinterpret_cast<const float4*>(ws + OFF_KP)
                         + (size_t)n * LSEQ * (EDIM / 4);
    const int* mrow = mask + nq * LSEQ;
    __hip_bfloat16* erow = en + (size_t)nq * (LSEQ * HNUM);

    // preload the wave's 16 mask values (wave-uniform -> scalar loads)
    int mks[16];
#pragma unroll
    for (int j = 0; j < 16; ++j) mks[j] = mrow[k0 + j];

#pragma unroll
    for (int j = 0; j < 16; ++j) {
        int k = k0 + j;
        if (mks[j]) {
            if ((lane & 7) == 0) erow[k * HNUM + h] = __float2bfloat16(-6.25e18f);
        } else {
            float4 rv = rel4[(size_t)k * (EDIM / 4) + lane];
            float4 kv = kp4[(size_t)k * (EDIM / 4) + lane];
            float p = rv.x * wv.x + rv.y * wv.y + rv.z * wv.z + rv.w * wv.w
                    + qv.x * kv.x + qv.y * kv.y + qv.z * kv.z + qv.w * kv.w;
            p += __shfl_xor(p, 1);
            p += __shfl_xor(p, 2);
            p += __shfl_xor(p, 4);
            if ((lane & 7) == 0) erow[k * HNUM + h] = __float2bfloat16((p + bsum) * 0.0625f);
        }
    }
}

// ---- tail: softmax + PV + Wout projection, 4 q-rows per block, 1024 thr -----
__global__ __launch_bounds__(1024)
void attn_tail4(const __hip_bfloat16* __restrict__ en, const float* __restrict__ ws,
                const float* __restrict__ bout, float* __restrict__ out) {
    __shared__ float att[4][HNUM][LSEQ + 1];   // ~32.9 KB
    __shared__ float part[16][4][EDIM];        // 64 KB
    __shared__ float accsm[4][EDIM];           // 4 KB

    int t = threadIdx.x;            // 0..1023
    int nq0 = blockIdx.x * 4;       // all 4 rows share n
    int n = nq0 >> 8;
    int lane = t & 63, wid = t >> 6;   // 16 waves
    int e0 = 4 * lane;
    int hh = lane >> 3;

    // load 4 energy rows: 4*2048 bf16; one uint4 (=8 bf16 = all heads of one k)
    // per thread: j = qq*256 + k
    {
        const uint4* enu = reinterpret_cast<const uint4*>(en + (size_t)nq0 * 2048);
        uint4 v = enu[t];
        int qq = t >> 8, k = t & 255;
        att[qq][0][k] = bf16_to_f32(v.x & 0xffffu);
        att[qq][1][k] = bf16_to_f32(v.x >> 16);
        att[qq][2][k] = bf16_to_f32(v.y & 0xffffu);
        att[qq][3][k] = bf16_to_f32(v.y >> 16);
        att[qq][4][k] = bf16_to_f32(v.z & 0xffffu);
        att[qq][5][k] = bf16_to_f32(v.z >> 16);
        att[qq][6][k] = bf16_to_f32(v.w & 0xffffu);
        att[qq][7][k] = bf16_to_f32(v.w >> 16);
    }
    __syncthreads();

    // softmax: 1024 threads = (4q x 8h) rows x 32 sub, each owns 8 elements
    {
        int row = t >> 5, sub = t & 31;   // row: qq*8+h
        int qq = row >> 3, h = row & 7;
        float m = -3.4e38f;
        for (int jj = 0; jj < 8; ++jj) m = fmaxf(m, att[qq][h][sub + jj * 32]);
        for (int off = 1; off < 32; off <<= 1) m = fmaxf(m, __shfl_xor(m, off));
        float ex[8];
        float ssum = 0.f;
        for (int jj = 0; jj < 8; ++jj) {
            float e_ = __expf(att[qq][h][sub + jj * 32] - m);
            ex[jj] = e_;
            ssum += e_;
        }
        for (int off = 1; off < 32; off <<= 1) ssum += __shfl_xor(ssum, off);
        float inv = 1.0f / ssum;
        for (int jj = 0; jj < 8; ++jj) att[qq][h][sub + jj * 32] = ex[jj] * inv;
    }
    __syncthreads();

    // PV: k split over 16 waves (16 each); each vv load feeds all 4 q-rows
    const float4* vp4 = reinterpret_cast<const float4*>(ws + OFF_VP)
                        + (size_t)n * LSEQ * (EDIM / 4);
    {
        float4 a0 = {0,0,0,0}, a1 = {0,0,0,0}, a2 = {0,0,0,0}, a3 = {0,0,0,0};
#pragma unroll 4
        for (int kk = 0; kk < 16; ++kk) {
            int k = wid * 16 + kk;
            float4 vv = vp4[(size_t)k * (EDIM / 4) + lane];
            float s0 = att[0][hh][k], s1 = att[1][hh][k];
            float s2 = att[2][hh][k], s3 = att[3][hh][k];
            a0.x += s0 * vv.x; a0.y += s0 * vv.y; a0.z += s0 * vv.z; a0.w += s0 * vv.w;
            a1.x += s1 * vv.x; a1.y += s1 * vv.y; a1.z += s1 * vv.z; a1.w += s1 * vv.w;
            a2.x += s2 * vv.x; a2.y += s2 * vv.y; a2.z += s2 * vv.z; a2.w += s2 * vv.w;
            a3.x += s3 * vv.x; a3.y += s3 * vv.y; a3.z += s3 * vv.z; a3.w += s3 * vv.w;
        }
        *reinterpret_cast<float4*>(&part[wid][0][e0]) = a0;
        *reinterpret_cast<float4*>(&part[wid][1][e0]) = a1;
        *reinterpret_cast<float4*>(&part[wid][2][e0]) = a2;
        *reinterpret_cast<float4*>(&part[wid][3][e0]) = a3;
    }
    __syncthreads();
    {
        int qq = t >> 8, e = t & 255;
        float s = 0.f;
#pragma unroll
        for (int w = 0; w < 16; ++w) s += part[w][qq][e];
        accsm[qq][e] = s;
    }
    __syncthreads();

    // final projection: e' split over 16 waves (16 each); w load feeds 4 rows
    const float4* wo4 = reinterpret_cast<const float4*>(ws + OFF_WOT);
    {
        float4 o0 = {0,0,0,0}, o1 = {0,0,0,0}, o2 = {0,0,0,0}, o3 = {0,0,0,0};
#pragma unroll 4
        for (int ee = 0; ee < 16; ++ee) {
            int ep = wid * 16 + ee;
            float a0 = accsm[0][ep], a1 = accsm[1][ep];
            float a2 = accsm[2][ep], a3 = accsm[3][ep];
            float4 w = wo4[(size_t)ep * (EDIM / 4) + lane];
            o0.x += a0 * w.x; o0.y += a0 * w.y; o0.z += a0 * w.z; o0.w += a0 * w.w;
            o1.x += a1 * w.x; o1.y += a1 * w.y; o1.z += a1 * w.z; o1.w += a1 * w.w;
            o2.x += a2 * w.x; o2.y += a2 * w.y; o2.z += a2 * w.z; o2.w += a2 * w.w;
            o3.x += a3 * w.x; o3.y += a3 * w.y; o3.z += a3 * w.z; o3.w += a3 * w.w;
        }
        *reinterpret_cast<float4*>(&part[wid][0][e0]) = o0;
        *reinterpret_cast<float4*>(&part[wid][1][e0]) = o1;
        *reinterpret_cast<float4*>(&part[wid][2][e0]) = o2;
        *reinterpret_cast<float4*>(&part[wid][3][e0]) = o3;
    }
    __syncthreads();
    {
        int qq = t >> 8, e = t & 255;
        float s = bout[e];
#pragma unroll
        for (int w = 0; w < 16; ++w) s += part[w][qq][e];
        out[(size_t)(nq0 + qq) * EDIM + e] = s;
    }
}

// ---- fallback fused kernel (R0, proven): used only if ws too small ----------
__global__ __launch_bounds__(256)
void attn_main(const float* __restrict__ relation, const int* __restrict__ mask,
               const float* __restrict__ ws, const float* __restrict__ bout,
               float* __restrict__ out) {
    __shared__ float qs[EDIM];
    __shared__ float wrf[EDIM];
    __shared__ int   mrow[LSEQ];
    __shared__ float energy[HNUM][LSEQ + 1];
    __shared__ float part[4][EDIM];
    __shared__ float accsm[EDIM];
    __shared__ float sb;

    int t = threadIdx.x;
    int bid = blockIdx.x;
    int n = bid >> 8, qi = bid & 255;
    int lane = t & 63, wid = t >> 6;

    qs[t]  = ws[OFF_QS + (n * LSEQ + qi) * EDIM + t];
    wrf[t] = ws[OFF_WR + (t & (DDIM - 1))];
    mrow[t] = mask[(n * LSEQ + qi) * LSEQ + t];
    if (t == 0) sb = ws[OFF_BS];
    __syncthreads();
    float bsum = sb;

    const float4* rel4 = reinterpret_cast<const float4*>(relation)
                         + (size_t)(n * LSEQ + qi) * LSEQ * (EDIM / 4);
    const float4* kp4  = reinterpret_cast<const float4*>(ws + OFF_KP)
                         + (size_t)n * LSEQ * (EDIM / 4);
    int e0 = 4 * lane;
    int hh = lane >> 3;
    float4 qv = *reinterpret_cast<const float4*>(&qs[e0]);
    float4 wv = *reinterpret_cast<const float4*>(&wrf[e0]);
    for (int it = 0; it < 64; ++it) {
        int k = it * 4 + wid;
        float4 rv = rel4[(size_t)k * (EDIM / 4) + lane];
        float4 kv = kp4[(size_t)k * (EDIM / 4) + lane];
        float p = rv.x * wv.x + rv.y * wv.y + rv.z * wv.z + rv.w * wv.w
                + qv.x * kv.x + qv.y * kv.y + qv.z * kv.z + qv.w * kv.w;
        p += __shfl_xor(p, 1);
        p += __shfl_xor(p, 2);
        p += __shfl_xor(p, 4);
        if ((lane & 7) == 0) {
            float val = mrow[k] ? -1e20f : (p + bsum);
            energy[hh][k] = val * 0.0625f;
        }
    }
    __syncthreads();

    {
        int h = t >> 5, sub = t & 31;
        float m = -3.4e38f;
        for (int jj = 0; jj < 8; ++jj) m = fmaxf(m, energy[h][sub + jj * 32]);
        for (int off = 1; off < 32; off <<= 1) m = fmaxf(m, __shfl_xor(m, off));
        float ex[8];
        float ssum = 0.f;
        for (int jj = 0; jj < 8; ++jj) {
            float e_ = __expf(energy[h][sub + jj * 32] - m);
            ex[jj] = e_;
            ssum += e_;
        }
        for (int off = 1; off < 32; off <<= 1) ssum += __shfl_xor(ssum, off);
        float inv = 1.0f / ssum;
        for (int jj = 0; jj < 8; ++jj) energy[h][sub + jj * 32] = ex[jj] * inv;
    }
    __syncthreads();

    const float4* vp4 = reinterpret_cast<const float4*>(ws + OFF_VP)
                        + (size_t)n * LSEQ * (EDIM / 4);
    {
        float4 a4 = {0.f, 0.f, 0.f, 0.f};
        for (int kk = 0; kk < 64; ++kk) {
            int k = wid * 64 + kk;
            float4 vv = vp4[(size_t)k * (EDIM / 4) + lane];
            float a = energy[hh][k];
            a4.x += a * vv.x; a4.y += a * vv.y; a4.z += a * vv.z; a4.w += a * vv.w;
        }
        *reinterpret_cast<float4*>(&part[wid][e0]) = a4;
    }
    __syncthreads();
    accsm[t] = part[0][t] + part[1][t] + part[2][t] + part[3][t];
    __syncthreads();

    const float4* wo4 = reinterpret_cast<const float4*>(ws + OFF_WOT);
    {
        float4 o4 = {0.f, 0.f, 0.f, 0.f};
        for (int ee = 0; ee < 64; ++ee) {
            int ep = wid * 64 + ee;
            float a = accsm[ep];
            float4 w = wo4[(size_t)ep * (EDIM / 4) + lane];
            o4.x += a * w.x; o4.y += a * w.y; o4.z += a * w.z; o4.w += a * w.w;
        }
        *reinterpret_cast<float4*>(&part[wid][e0]) = o4;
    }
    __syncthreads();
    out[(n * LSEQ + qi) * EDIM + t] =
        part[0][t] + part[1][t] + part[2][t] + part[3][t] + bout[t];
}

extern "C" void kernel_launch(void* const* d_in, const int* in_sizes, int n_in,
                              void* d_out, int out_size, void* d_ws, size_t ws_size,
                              hipStream_t stream) {
    const float* values   = (const float*)d_in[0];
    const float* keys     = (const float*)d_in[1];
    const float* query    = (const float*)d_in[2];
    const int*   mask     = (const int*)d_in[3];
    const float* relation = (const float*)d_in[4];
    const float* Wv    = (const float*)d_in[5];
    const float* Wk    = (const float*)d_in[6];
    const float* Wq    = (const float*)d_in[7];
    const float* Wr    = (const float*)d_in[8];
    const float* Wfuse = (const float*)d_in[9];
    const float* bfuse = (const float*)d_in[10];
    const float* Wout  = (const float*)d_in[11];
    const float* bout  = (const float*)d_in[12];
    float* ws  = (float*)d_ws;
    float* out = (float*)d_out;

    prep_all<<<273, 256, 0, stream>>>(query, keys, values,
                                      Wq, Wk, Wv, Wfuse, bfuse,
                                      Wr, Wout, ws);

    if (ws_size >= (size_t)WS_NEED_FLOATS * sizeof(float)) {
        __hip_bfloat16* en = reinterpret_cast<__hip_bfloat16*>(ws + OFF_EN);
        energy_kernel<<<4096, 256, 0, stream>>>(relation, mask, ws, en);
        attn_tail4<<<NBAT * LSEQ / 4, 1024, 0, stream>>>(en, ws, bout, out);
    } else {
        attn_main<<<NBAT * LSEQ, 256, 0, stream>>>(relation, mask, ws, bout, out);
    }
}